// Round 2
// baseline (921.864 us; speedup 1.0000x reference)
//
#include <hip/hip_runtime.h>
#include <hip/hip_bf16.h>

// AgentEncoder: B=256, A=512, T=21, DIM=128, SC=6, NHEAD=4, HD=32
// Float dtype (f32 vs bf16) detected at runtime from bit patterns; both
// template variants launched, non-matching one early-exits.
// valid_mask storage format detected at runtime (i32 / u8 / f32 / bf16).

#define BB 256
#define AAG 512
#define TT 21
#define NAG (BB * AAG)

typedef __hip_bfloat16 bf16;

__device__ int   g_dtype;                // 1 = bf16, 0 = f32
__device__ int   g_mask_mode;            // 0=i32, 1=u8, 2=f32, 3=bf16
__device__ float g_w1t[9][3][32];        // conv1 w, [ic][h][oc]
__device__ float g_b1[32];
__device__ float g_w2t[32][3][64];       // conv2 w, [ic][h][oc]
__device__ float g_b2[64];
__device__ float g_w3t[64][3][128];      // conv3 w, [ic][h][oc]
__device__ float g_b3[128];

template <int DT>
__device__ __forceinline__ float ldf(const void* p, long i) {
    if (DT) return __bfloat162float(((const bf16*)p)[i]);
    return ((const float*)p)[i];
}
template <int DT>
__device__ __forceinline__ void stf(void* p, long i, float v) {
    if (DT) ((bf16*)p)[i] = __float2bfloat16(v);
    else    ((float*)p)[i] = v;
}

__device__ __forceinline__ bool mask_at(const void* p, long i, int mode) {
    if (mode == 0) return ((const int*)p)[i] != 0;
    if (mode == 1) return ((const unsigned char*)p)[i] != 0;
    if (mode == 2) return ((const float*)p)[i] != 0.f;
    return (((const unsigned short*)p)[i] & 0x7fff) != 0;
}

// ---------------- dtype + mask detection (1 block) ----------------
__global__ void detect_kernel(const unsigned int* __restrict__ pw,
                              const unsigned char* __restrict__ m) {
    __shared__ int cls[4];
    __shared__ int mv;
    __shared__ int good;
    int tid = threadIdx.x;
    if (tid < 4) cls[tid] = 0;
    if (tid == 0) { mv = 0; good = 0; }
    __syncthreads();

    // --- float dtype: 1024 words = 2048 halfwords of `position` ---
    int g = 0;
    for (int i = tid; i < 1024; i += 256) {
        unsigned int w = pw[i];
        unsigned int h0 = w & 0xffffu, h1 = w >> 16;
        unsigned int e0 = (h0 >> 7) & 0xff, e1 = (h1 >> 7) & 0xff;
        if (h0 == 0 || (e0 >= 90 && e0 <= 160)) g++;
        if (h1 == 0 || (e1 >= 90 && e1 <= 160)) g++;
    }
    atomicAdd(&good, g);

    // --- mask storage format: first 4096 bytes ---
    int l0 = 0, l1 = 0, l2 = 0, l3 = 0, lm = 0;
    for (int i = tid; i < 4096; i += 256) {
        int v = m[i];
        if (v) {
            switch (i & 3) { case 0: l0 = 1; break; case 1: l1 = 1; break;
                             case 2: l2 = 1; break; default: l3 = 1; }
            if (v > lm) lm = v;
        }
    }
    if (l0) atomicOr(&cls[0], 1);
    if (l1) atomicOr(&cls[1], 1);
    if (l2) atomicOr(&cls[2], 1);
    if (l3) atomicOr(&cls[3], 1);
    atomicMax(&mv, lm);
    __syncthreads();

    if (tid == 0) {
        g_dtype = (good >= 1740) ? 1 : 0;   // >=85% plausible bf16 halfwords
        int mode;
        if (!cls[1] && !cls[2] && !cls[3]) mode = 0;       // i32
        else if (!cls[0] && !cls[1])       mode = 2;       // f32
        else if (mv <= 1)                  mode = 1;       // u8
        else                               mode = 3;       // bf16
        g_mask_mode = mode;
    }
}

// ---------------- weight transpose/upcast ----------------
template <int DT>
__global__ void prep_weights_kernel(const void* __restrict__ w1, const void* __restrict__ b1,
                                    const void* __restrict__ w2, const void* __restrict__ b2,
                                    const void* __restrict__ w3, const void* __restrict__ b3) {
    if (g_dtype != DT) return;
    int tid = blockIdx.x * blockDim.x + threadIdx.x;
    int nt = gridDim.x * blockDim.x;
    for (int i = tid; i < 32 * 9 * 3; i += nt) {
        int o = i / 27, r = i % 27, ic = r / 3, h = r % 3;
        g_w1t[ic][h][o] = ldf<DT>(w1, i);
    }
    for (int i = tid; i < 32; i += nt) g_b1[i] = ldf<DT>(b1, i);
    for (int i = tid; i < 64 * 32 * 3; i += nt) {
        int o = i / 96, r = i % 96, ic = r / 3, h = r % 3;
        g_w2t[ic][h][o] = ldf<DT>(w2, i);
    }
    for (int i = tid; i < 64; i += nt) g_b2[i] = ldf<DT>(b2, i);
    for (int i = tid; i < 128 * 64 * 3; i += nt) {
        int o = i / 192, r = i % 192, ic = r / 3, h = r % 3;
        g_w3t[ic][h][o] = ldf<DT>(w3, i);
    }
    for (int i = tid; i < 128; i += nt) g_b3[i] = ldf<DT>(b3, i);
}

// ---------------- stage 1: features + 3 convs + mean + type_emb ----------------
// block = 256 threads, 8 agents per block.
template <int DT>
__global__ __launch_bounds__(256) void stage1_kernel(
    const void* __restrict__ pos, const void* __restrict__ heading,
    const void* __restrict__ vel, const void* __restrict__ shp,
    const void* __restrict__ vmask, const int* __restrict__ category,
    const void* __restrict__ type_emb, void* __restrict__ out) {
    if (g_dtype != DT) return;
    __shared__ float s_w1[9][3][32];
    __shared__ float s_w2[32][3][64];
    __shared__ float s_b1[32];
    __shared__ float s_b2[64];
    __shared__ float s_b3[128];
    __shared__ float s_feat[8][9][21];   // idx 0..19 data, 20 = SAME right-pad (0)
    __shared__ float s_h1[8][32][11];    // idx 0..9 data, 10 = pad (0)
    __shared__ float s_h2[8][64][8];     // idx 0 pad, 1..5 data, 6 pad, 7 unused
    __shared__ int   s_valid[8];

    const int tid = threadIdx.x;
    const int mode = g_mask_mode;
    const long agent0 = (long)blockIdx.x * 8;

    // weights -> LDS
    {
        const float* src1 = &g_w1t[0][0][0];
        float* dst1 = &s_w1[0][0][0];
        for (int i = tid; i < 864; i += 256) dst1[i] = src1[i];
        const float* src2 = &g_w2t[0][0][0];
        float* dst2 = &s_w2[0][0][0];
        for (int i = tid; i < 6144; i += 256) dst2[i] = src2[i];
        if (tid < 32) s_b1[tid] = g_b1[tid];
        if (tid < 64) s_b2[tid] = g_b2[tid];
        if (tid < 128) s_b3[tid] = g_b3[tid];
    }

    // P0: feature build (g = tid>>5, t = tid&31)
    {
        int g = tid >> 5, t = tid & 31;
        long agent = agent0 + g;
        long base = agent * TT + t;
        bool vmt = (t < TT) ? mask_at(vmask, base, mode) : false;
        unsigned long long bal = __ballot(vmt);
        int lane = tid & 63;
        if (lane == 0) s_valid[g] = (bal & 0xffffffffull) ? 1 : 0;
        else if (lane == 32) s_valid[g] = (bal >> 32) ? 1 : 0;
        if (t < TT - 1) {
            bool m2 = vmt && mask_at(vmask, base + 1, mode);
            float px0 = ldf<DT>(pos, base * 2),     py0 = ldf<DT>(pos, base * 2 + 1);
            float px1 = ldf<DT>(pos, base * 2 + 2), py1 = ldf<DT>(pos, base * 2 + 3);
            float vx0 = ldf<DT>(vel, base * 2),     vy0 = ldf<DT>(vel, base * 2 + 1);
            float vx1 = ldf<DT>(vel, base * 2 + 2), vy1 = ldf<DT>(vel, base * 2 + 3);
            float h0 = ldf<DT>(heading, base), h1 = ldf<DT>(heading, base + 1);
            float sx = ldf<DT>(shp, base * 2 + 2), sy = ldf<DT>(shp, base * 2 + 3);
            float dh = m2 ? (h1 - h0) : 0.f;   // masked -> 0 -> cos=1, sin=0 (matches ref)
            float sn = sinf(dh), cn = cosf(dh);
            s_feat[g][0][t] = m2 ? (px1 - px0) : 0.f;
            s_feat[g][1][t] = m2 ? (py1 - py0) : 0.f;
            s_feat[g][2][t] = m2 ? (vx1 - vx0) : 0.f;
            s_feat[g][3][t] = m2 ? (vy1 - vy0) : 0.f;
            s_feat[g][4][t] = cn;
            s_feat[g][5][t] = sn;
            s_feat[g][6][t] = sx;
            s_feat[g][7][t] = sy;
            s_feat[g][8][t] = m2 ? 1.f : 0.f;
        } else if (t == TT - 1) {
#pragma unroll
            for (int c = 0; c < 9; c++) s_feat[g][c][20] = 0.f;
        }
    }
    __syncthreads();

    // P1: conv1 9->32, L20->10, stride2, pad(0,1)
    {
        int oc = tid & 31, g = tid >> 5;
        float acc[10];
#pragma unroll
        for (int p = 0; p < 10; p++) acc[p] = 0.f;
        for (int ic = 0; ic < 9; ic++) {
            float w0 = s_w1[ic][0][oc], w1 = s_w1[ic][1][oc], w2 = s_w1[ic][2][oc];
            float rf[21];
#pragma unroll
            for (int j = 0; j < 21; j++) rf[j] = s_feat[g][ic][j];
#pragma unroll
            for (int p = 0; p < 10; p++)
                acc[p] = fmaf(rf[2 * p], w0, fmaf(rf[2 * p + 1], w1, fmaf(rf[2 * p + 2], w2, acc[p])));
        }
        float b = s_b1[oc];
#pragma unroll
        for (int p = 0; p < 10; p++) s_h1[g][oc][p] = fmaxf(acc[p] + b, 0.f);
        s_h1[g][oc][10] = 0.f;
    }
    __syncthreads();

    // P2: conv2 32->64, L10->5, stride2, pad(0,1)
    {
        int oc = tid & 31, g = tid >> 5;
        float a0[5], a1[5];
#pragma unroll
        for (int p = 0; p < 5; p++) { a0[p] = 0.f; a1[p] = 0.f; }
        for (int ic = 0; ic < 32; ic++) {
            float w00 = s_w2[ic][0][oc],      w01 = s_w2[ic][1][oc],      w02 = s_w2[ic][2][oc];
            float w10 = s_w2[ic][0][oc + 32], w11 = s_w2[ic][1][oc + 32], w12 = s_w2[ic][2][oc + 32];
            float rh[11];
#pragma unroll
            for (int j = 0; j < 11; j++) rh[j] = s_h1[g][ic][j];
#pragma unroll
            for (int p = 0; p < 5; p++) {
                a0[p] = fmaf(rh[2 * p], w00, fmaf(rh[2 * p + 1], w01, fmaf(rh[2 * p + 2], w02, a0[p])));
                a1[p] = fmaf(rh[2 * p], w10, fmaf(rh[2 * p + 1], w11, fmaf(rh[2 * p + 2], w12, a1[p])));
            }
        }
        float b0 = s_b2[oc], b1v = s_b2[oc + 32];
#pragma unroll
        for (int p = 0; p < 5; p++) {
            s_h2[g][oc][p + 1] = fmaxf(a0[p] + b0, 0.f);
            s_h2[g][oc + 32][p + 1] = fmaxf(a1[p] + b1v, 0.f);
        }
        s_h2[g][oc][0] = 0.f;      s_h2[g][oc][6] = 0.f;      s_h2[g][oc][7] = 0.f;
        s_h2[g][oc + 32][0] = 0.f; s_h2[g][oc + 32][6] = 0.f; s_h2[g][oc + 32][7] = 0.f;
    }
    __syncthreads();

    // P3: conv3 64->128, L5->3, stride2, pad(1,1) + mean + epilogue
    {
        int ocp = tid & 63, slice = tid >> 6;
        float acc[2][6];
#pragma unroll
        for (int j = 0; j < 2; j++)
#pragma unroll
            for (int q = 0; q < 6; q++) acc[j][q] = 0.f;
        for (int ic = 0; ic < 64; ic++) {
            float w00 = g_w3t[ic][0][ocp],      w01 = g_w3t[ic][1][ocp],      w02 = g_w3t[ic][2][ocp];
            float w10 = g_w3t[ic][0][ocp + 64], w11 = g_w3t[ic][1][ocp + 64], w12 = g_w3t[ic][2][ocp + 64];
#pragma unroll
            for (int j = 0; j < 2; j++) {
                int g = slice * 2 + j;
                float r0 = s_h2[g][ic][0], r1 = s_h2[g][ic][1], r2 = s_h2[g][ic][2],
                      r3 = s_h2[g][ic][3], r4 = s_h2[g][ic][4], r5 = s_h2[g][ic][5], r6 = s_h2[g][ic][6];
                acc[j][0] = fmaf(r0, w00, fmaf(r1, w01, fmaf(r2, w02, acc[j][0])));
                acc[j][1] = fmaf(r2, w00, fmaf(r3, w01, fmaf(r4, w02, acc[j][1])));
                acc[j][2] = fmaf(r4, w00, fmaf(r5, w01, fmaf(r6, w02, acc[j][2])));
                acc[j][3] = fmaf(r0, w10, fmaf(r1, w11, fmaf(r2, w12, acc[j][3])));
                acc[j][4] = fmaf(r2, w10, fmaf(r3, w11, fmaf(r4, w12, acc[j][4])));
                acc[j][5] = fmaf(r4, w10, fmaf(r5, w11, fmaf(r6, w12, acc[j][5])));
            }
        }
        float bb0 = s_b3[ocp], bb1 = s_b3[ocp + 64];
#pragma unroll
        for (int j = 0; j < 2; j++) {
            int g = slice * 2 + j;
            long agent = agent0 + g;
            int cat = category[agent];
            int valid = s_valid[g];
            float e0 = (fmaxf(acc[j][0] + bb0, 0.f) + fmaxf(acc[j][1] + bb0, 0.f) +
                        fmaxf(acc[j][2] + bb0, 0.f)) * (1.f / 3.f);
            float e1 = (fmaxf(acc[j][3] + bb1, 0.f) + fmaxf(acc[j][4] + bb1, 0.f) +
                        fmaxf(acc[j][5] + bb1, 0.f)) * (1.f / 3.f);
            if (!valid) { e0 = 0.f; e1 = 0.f; }
            float t0 = ldf<DT>(type_emb, cat * 128 + ocp);
            float t1 = ldf<DT>(type_emb, cat * 128 + ocp + 64);
            stf<DT>(out, agent * 128 + ocp, e0 + t0);
            stf<DT>(out, agent * 128 + ocp + 64, e1 + t1);
        }
    }
}

// ---------------- stage 2: ego cross-attention, overwrites row a=0 ----------------
template <int DT>
__global__ __launch_bounds__(128) void stage2_kernel(
    const void* __restrict__ cs, const int* __restrict__ category,
    const void* __restrict__ se_w, const void* __restrict__ se_b,
    const void* __restrict__ pe, const void* __restrict__ query,
    const void* __restrict__ ipw, const void* __restrict__ ipb,
    const void* __restrict__ opw, const void* __restrict__ opb,
    const void* __restrict__ type_emb, void* __restrict__ out) {
    if (g_dtype != DT) return;
    int b = blockIdx.x, d = threadIdx.x;
    __shared__ float s_xe[6][128];
    __shared__ float s_qu[128];
    __shared__ float s_q[128];
    __shared__ float s_k[6][128];
    __shared__ float s_v[6][128];
    __shared__ float s_att[4][6];
    __shared__ float s_o[128];

    s_qu[d] = ldf<DT>(query, d);
#pragma unroll
    for (int s = 0; s < 6; s++) {
        float ego = ldf<DT>(cs, b * 6 + s);
        s_xe[s][d] = fmaf(ego, ldf<DT>(se_w, s * 128 + d),
                          ldf<DT>(se_b, s * 128 + d) + ldf<DT>(pe, s * 128 + d));
    }
    __syncthreads();

    float accq = ldf<DT>(ipb, d);
    float bk = ldf<DT>(ipb, 128 + d), bv = ldf<DT>(ipb, 256 + d);
    float acck[6], accv[6];
#pragma unroll
    for (int s = 0; s < 6; s++) { acck[s] = bk; accv[s] = bv; }
    for (int e = 0; e < 128; e++) {
        float wqe = ldf<DT>(ipw, (long)d * 128 + e);
        accq = fmaf(s_qu[e], wqe, accq);
        float wke = ldf<DT>(ipw, (long)(128 + d) * 128 + e);
        float wve = ldf<DT>(ipw, (long)(256 + d) * 128 + e);
#pragma unroll
        for (int s = 0; s < 6; s++) {
            float xe = s_xe[s][e];
            acck[s] = fmaf(xe, wke, acck[s]);
            accv[s] = fmaf(xe, wve, accv[s]);
        }
    }
    s_q[d] = accq;
#pragma unroll
    for (int s = 0; s < 6; s++) { s_k[s][d] = acck[s]; s_v[s][d] = accv[s]; }
    __syncthreads();

    if (d < 4) {  // one thread per head
        float sc[6];
        float mx = -1e30f;
#pragma unroll
        for (int s = 0; s < 6; s++) {
            float t = 0.f;
            for (int q = 0; q < 32; q++) t = fmaf(s_q[d * 32 + q], s_k[s][d * 32 + q], t);
            t *= 0.17677669529663687f;  // 1/sqrt(32)
            sc[s] = t;
            mx = fmaxf(mx, t);
        }
        float sum = 0.f;
#pragma unroll
        for (int s = 0; s < 6; s++) { sc[s] = expf(sc[s] - mx); sum += sc[s]; }
        float inv = 1.f / sum;
#pragma unroll
        for (int s = 0; s < 6; s++) s_att[d][s] = sc[s] * inv;
    }
    __syncthreads();

    {
        int h = d >> 5;
        float o = 0.f;
#pragma unroll
        for (int s = 0; s < 6; s++) o = fmaf(s_att[h][s], s_v[s][d], o);
        s_o[d] = o;
    }
    __syncthreads();

    float acc = ldf<DT>(opb, d);
    for (int e = 0; e < 128; e++) acc = fmaf(s_o[e], ldf<DT>(opw, (long)d * 128 + e), acc);
    int cat = category[(long)b * AAG];
    stf<DT>(out, (long)b * AAG * 128 + d, acc + ldf<DT>(type_emb, cat * 128 + d));
}

extern "C" void kernel_launch(void* const* d_in, const int* in_sizes, int n_in,
                              void* d_out, int out_size, void* d_ws, size_t ws_size,
                              hipStream_t stream) {
    const void* position      = d_in[0];
    const void* heading       = d_in[1];
    const void* velocity      = d_in[2];
    const void* shape         = d_in[3];
    const void* current_state = d_in[4];
    const int*  category      = (const int*)d_in[5];
    const void* valid_mask    = d_in[6];
    const void* conv1_w = d_in[7];
    const void* conv1_b = d_in[8];
    const void* conv2_w = d_in[9];
    const void* conv2_b = d_in[10];
    const void* conv3_w = d_in[11];
    const void* conv3_b = d_in[12];
    const void* se_w    = d_in[13];
    const void* se_b    = d_in[14];
    const void* pos_embed = d_in[15];
    const void* query     = d_in[16];
    const void* in_proj_w = d_in[17];
    const void* in_proj_b = d_in[18];
    const void* out_proj_w = d_in[19];
    const void* out_proj_b = d_in[20];
    const void* type_emb   = d_in[21];

    hipLaunchKernelGGL(detect_kernel, dim3(1), dim3(256), 0, stream,
                       (const unsigned int*)position, (const unsigned char*)valid_mask);

    hipLaunchKernelGGL(prep_weights_kernel<0>, dim3(64), dim3(256), 0, stream,
                       conv1_w, conv1_b, conv2_w, conv2_b, conv3_w, conv3_b);
    hipLaunchKernelGGL(prep_weights_kernel<1>, dim3(64), dim3(256), 0, stream,
                       conv1_w, conv1_b, conv2_w, conv2_b, conv3_w, conv3_b);

    hipLaunchKernelGGL(stage1_kernel<0>, dim3(NAG / 8), dim3(256), 0, stream,
                       position, heading, velocity, shape, valid_mask, category, type_emb, d_out);
    hipLaunchKernelGGL(stage1_kernel<1>, dim3(NAG / 8), dim3(256), 0, stream,
                       position, heading, velocity, shape, valid_mask, category, type_emb, d_out);

    hipLaunchKernelGGL(stage2_kernel<0>, dim3(BB), dim3(128), 0, stream,
                       current_state, category, se_w, se_b, pos_embed, query,
                       in_proj_w, in_proj_b, out_proj_w, out_proj_b, type_emb, d_out);
    hipLaunchKernelGGL(stage2_kernel<1>, dim3(BB), dim3(128), 0, stream,
                       current_state, category, se_w, se_b, pos_embed, query,
                       in_proj_w, in_proj_b, out_proj_w, out_proj_b, type_emb, d_out);
}

// Round 3
// 324.846 us; speedup vs baseline: 2.8378x; 2.8378x over previous
//
#include <hip/hip_runtime.h>
#include <hip/hip_bf16.h>

// AgentEncoder: B=256, A=512, T=21, DIM=128, SC=6, NHEAD=4, HD=32
// Stage1 rewritten on MFMA (mfma_f32_16x16x32_bf16): conv1/2/3 as per-tap
// K-sliced GEMMs, activations in LDS transposed [t][ic] (B-frag = 1x b128),
// weights pre-padded [oc][k] bf16 (A-frag = 1x 16B global, hoisted per Mtile).
// LDS strides padded 16B-aligned, != 0 mod 128B, to break bank aliasing.
// Float dtype (f32 vs bf16) + mask format detected at runtime.

#define BB 256
#define AAG 512
#define TT 21
#define NAG (BB * AAG)

typedef __hip_bfloat16 bf16;
typedef __attribute__((ext_vector_type(8))) short s8v;   // 8 bf16 = 4 VGPR
typedef __attribute__((ext_vector_type(4))) float f4v;   // mfma acc

__device__ int g_dtype;        // 1 = bf16 inputs, 0 = f32 inputs
__device__ int g_mask_mode;    // 0=i32, 1=u8, 2=f32, 3=bf16
__device__ __align__(16) short g_w1p[32 * 64];    // [oc][k=tap*16+ic], pad0
__device__ __align__(16) short g_w2p[64 * 96];    // [oc][k=tap*32+ic]
__device__ __align__(16) short g_w3p[128 * 192];  // [oc][k=tap*64+ic]
__device__ __align__(16) float g_b1[32];
__device__ __align__(16) float g_b2[64];
__device__ __align__(16) float g_b3[128];

template <int DT>
__device__ __forceinline__ float ldf(const void* p, long i) {
    if (DT) return __bfloat162float(((const bf16*)p)[i]);
    return ((const float*)p)[i];
}
template <int DT>
__device__ __forceinline__ void stf(void* p, long i, float v) {
    if (DT) ((bf16*)p)[i] = __float2bfloat16(v);
    else    ((float*)p)[i] = v;
}
__device__ __forceinline__ unsigned short f2bu(float x) {
    bf16 b = __float2bfloat16(x);
    union { bf16 b; unsigned short u; } cv; cv.b = b; return cv.u;
}
__device__ __forceinline__ float bu2f(unsigned short u) {
    union { unsigned int i; float f; } cv; cv.i = ((unsigned int)u) << 16; return cv.f;
}
__device__ __forceinline__ bool mask_at(const void* p, long i, int mode) {
    if (mode == 0) return ((const int*)p)[i] != 0;
    if (mode == 1) return ((const unsigned char*)p)[i] != 0;
    if (mode == 2) return ((const float*)p)[i] != 0.f;
    return (((const unsigned short*)p)[i] & 0x7fff) != 0;
}

// ---------------- dtype + mask detection (1 block) ----------------
__global__ void detect_kernel(const unsigned int* __restrict__ pw,
                              const unsigned char* __restrict__ m) {
    __shared__ int cls[4];
    __shared__ int mv;
    __shared__ int good;
    int tid = threadIdx.x;
    if (tid < 4) cls[tid] = 0;
    if (tid == 0) { mv = 0; good = 0; }
    __syncthreads();
    int g = 0;
    for (int i = tid; i < 1024; i += 256) {
        unsigned int w = pw[i];
        unsigned int h0 = w & 0xffffu, h1 = w >> 16;
        unsigned int e0 = (h0 >> 7) & 0xff, e1 = (h1 >> 7) & 0xff;
        if (h0 == 0 || (e0 >= 90 && e0 <= 160)) g++;
        if (h1 == 0 || (e1 >= 90 && e1 <= 160)) g++;
    }
    atomicAdd(&good, g);
    int l0 = 0, l1 = 0, l2 = 0, l3 = 0, lm = 0;
    for (int i = tid; i < 4096; i += 256) {
        int v = m[i];
        if (v) {
            switch (i & 3) { case 0: l0 = 1; break; case 1: l1 = 1; break;
                             case 2: l2 = 1; break; default: l3 = 1; }
            if (v > lm) lm = v;
        }
    }
    if (l0) atomicOr(&cls[0], 1);
    if (l1) atomicOr(&cls[1], 1);
    if (l2) atomicOr(&cls[2], 1);
    if (l3) atomicOr(&cls[3], 1);
    atomicMax(&mv, lm);
    __syncthreads();
    if (tid == 0) {
        g_dtype = (good >= 1740) ? 1 : 0;
        int mode;
        if (!cls[1] && !cls[2] && !cls[3]) mode = 0;
        else if (!cls[0] && !cls[1])       mode = 2;
        else if (mv <= 1)                  mode = 1;
        else                               mode = 3;
        g_mask_mode = mode;
    }
}

// ---------------- weight pad/transpose/cast ----------------
template <int DT>
__global__ void prep_weights_kernel(const void* __restrict__ w1, const void* __restrict__ b1,
                                    const void* __restrict__ w2, const void* __restrict__ b2,
                                    const void* __restrict__ w3, const void* __restrict__ b3) {
    if (g_dtype != DT) return;
    int tid = blockIdx.x * blockDim.x + threadIdx.x;
    int nt = gridDim.x * blockDim.x;
    for (int i = tid; i < 32 * 64; i += nt) {
        int oc = i >> 6, k = i & 63, tap = k >> 4, ic = k & 15;
        float v = (tap < 3 && ic < 9) ? ldf<DT>(w1, oc * 27 + ic * 3 + tap) : 0.f;
        g_w1p[i] = (short)f2bu(v);
    }
    for (int i = tid; i < 64 * 96; i += nt) {
        int oc = i / 96, k = i % 96, tap = k >> 5, ic = k & 31;
        g_w2p[i] = (short)f2bu(ldf<DT>(w2, oc * 96 + ic * 3 + tap));
    }
    for (int i = tid; i < 128 * 192; i += nt) {
        int oc = i / 192, k = i % 192, tap = k >> 6, ic = k & 63;
        g_w3p[i] = (short)f2bu(ldf<DT>(w3, oc * 192 + ic * 3 + tap));
    }
    for (int i = tid; i < 32; i += nt) g_b1[i] = ldf<DT>(b1, i);
    for (int i = tid; i < 64; i += nt) g_b2[i] = ldf<DT>(b2, i);
    for (int i = tid; i < 128; i += nt) g_b3[i] = ldf<DT>(b3, i);
}

// ---------------- stage 1: 16 agents/block, 4 waves ----------------
// LDS layout (shorts). Strides 16B-aligned, agent/row strides != 0 mod 64 shorts.
#define FEAT_RS 24     // feat row stride (22 rows: t=0..19 data, 20/21 zero; ch 0..15 used)
#define FEAT_AS 528    // 22*24
#define H1_RS 40       // h1 rows t=0..10 (10 = zero pad), ch 0..31
#define H1_AS 440      // 11*40
#define H2_RS 72       // h2 rows r=t+1: 0..6 (0,6 zero), ch 0..63
#define H2_AS 504      // 7*72
#define C3_AS 384      // c3 [ag][p][oc]: 3*128, reuses feat region
#define OFF_H1 8448    // shorts (16896 B)
#define OFF_H2 15488   // shorts (30976 B)
#define OFF_VALID 47104 // bytes
#define SMEM_BYTES 47168

#define MFMA16(a, b, c) __builtin_amdgcn_mfma_f32_16x16x32_bf16((a), (b), (c), 0, 0, 0)

template <int DT>
__global__ __launch_bounds__(256) void stage1_kernel(
    const void* __restrict__ pos, const void* __restrict__ heading,
    const void* __restrict__ vel, const void* __restrict__ shp,
    const void* __restrict__ vmask, const int* __restrict__ category,
    const void* __restrict__ type_emb, void* __restrict__ out) {
    if (g_dtype != DT) return;
    __shared__ __align__(16) char smem[SMEM_BYTES];
    short* feat = (short*)smem;
    short* h1 = (short*)smem + OFF_H1;
    short* h2 = (short*)smem + OFF_H2;
    short* c3 = (short*)smem;               // reuse: feat dead after conv1
    int* s_valid = (int*)(smem + OFF_VALID);

    const int tid = threadIdx.x;
    const int wave = tid >> 6, lane = tid & 63;
    const int col = lane & 15, quad = lane >> 4;
    const long agent0 = (long)blockIdx.x * 16;
    const int mode = g_mask_mode;

    // ---- phase 0: zero pad rows + valid init ----
    if (tid < 16) s_valid[tid] = 0;
    {
        unsigned int* h1u = (unsigned int*)h1;          // h1 row 10 zero
        int ag = tid >> 4, c = tid & 15;
        h1u[ag * 220 + 200 + c] = 0;
        unsigned int* h2u = (unsigned int*)h2;          // h2 rows 0 & 6 zero
        for (int i = tid; i < 1024; i += 256) {
            int a2 = i >> 6, r = (i >> 5) & 1, cc = i & 31;
            h2u[a2 * 252 + r * 216 + cc] = 0;
        }
    }
    __syncthreads();

    // ---- phase 1: feature build (bf16, [ag][t][ch16]) ----
    for (int idx = tid; idx < 16 * 22; idx += 256) {
        int ag = idx / 22, t = idx % 22;
        short* row = feat + ag * FEAT_AS + t * FEAT_RS;
        if (t >= 20) {
            *(uint4*)row = make_uint4(0, 0, 0, 0);
            *(uint4*)(row + 8) = make_uint4(0, 0, 0, 0);
            if (t == 20) {
                long base = (agent0 + ag) * TT + 20;
                if (mask_at(vmask, base, mode)) atomicOr(&s_valid[ag], 1);
            }
        } else {
            long base = (agent0 + ag) * TT + t;
            bool vmt = mask_at(vmask, base, mode);
            if (vmt) atomicOr(&s_valid[ag], 1);
            bool m2 = vmt && mask_at(vmask, base + 1, mode);
            float px0 = ldf<DT>(pos, base * 2),     py0 = ldf<DT>(pos, base * 2 + 1);
            float px1 = ldf<DT>(pos, base * 2 + 2), py1 = ldf<DT>(pos, base * 2 + 3);
            float vx0 = ldf<DT>(vel, base * 2),     vy0 = ldf<DT>(vel, base * 2 + 1);
            float vx1 = ldf<DT>(vel, base * 2 + 2), vy1 = ldf<DT>(vel, base * 2 + 3);
            float hh0 = ldf<DT>(heading, base), hh1 = ldf<DT>(heading, base + 1);
            float sx = ldf<DT>(shp, base * 2 + 2), sy = ldf<DT>(shp, base * 2 + 3);
            float dh = m2 ? (hh1 - hh0) : 0.f;      // masked: cos=1, sin=0 (ref)
            float sn = sinf(dh), cn = cosf(dh);
            unsigned int p0 = f2bu(m2 ? px1 - px0 : 0.f) | ((unsigned int)f2bu(m2 ? py1 - py0 : 0.f) << 16);
            unsigned int p1 = f2bu(m2 ? vx1 - vx0 : 0.f) | ((unsigned int)f2bu(m2 ? vy1 - vy0 : 0.f) << 16);
            unsigned int p2 = f2bu(cn) | ((unsigned int)f2bu(sn) << 16);
            unsigned int p3 = f2bu(sx) | ((unsigned int)f2bu(sy) << 16);
            unsigned int p4 = (unsigned int)f2bu(m2 ? 1.f : 0.f);
            *(uint4*)row = make_uint4(p0, p1, p2, p3);
            *(uint4*)(row + 8) = make_uint4(p4, 0, 0, 0);
        }
    }
    __syncthreads();

    // ---- conv1: M=32 (2 Mt), K=64 (2 slices, taps 0..2 + zero tap3), N=160 (10 Nt) ----
    {
        int Mt = wave >> 1;
        int oc = Mt * 16 + col;
        s8v a0 = *(const s8v*)(g_w1p + oc * 64 + quad * 8);
        s8v a1 = *(const s8v*)(g_w1p + oc * 64 + 32 + quad * 8);
        int k0 = quad * 8, k1 = 32 + quad * 8;
        int tap0 = k0 >> 4, ic0 = k0 & 15;
        int tap1 = k1 >> 4, ic1 = k1 & 15;
        int ocr = Mt * 16 + quad * 4;
        f4v bia = *(const f4v*)(g_b1 + ocr);
#pragma unroll
        for (int i = 0; i < 5; i++) {
            int Nt = (wave & 1) * 5 + i;
            int n = Nt * 16 + col;
            int ag = n / 10, p = n % 10;
            const short* bb = feat + ag * FEAT_AS + 2 * p * FEAT_RS;
            s8v b0 = *(const s8v*)(bb + tap0 * FEAT_RS + ic0);
            s8v b1 = *(const s8v*)(bb + tap1 * FEAT_RS + ic1);
            f4v acc = {0.f, 0.f, 0.f, 0.f};
            acc = MFMA16(a0, b0, acc);
            acc = MFMA16(a1, b1, acc);
            unsigned int lo = f2bu(fmaxf(acc[0] + bia[0], 0.f)) | ((unsigned int)f2bu(fmaxf(acc[1] + bia[1], 0.f)) << 16);
            unsigned int hi = f2bu(fmaxf(acc[2] + bia[2], 0.f)) | ((unsigned int)f2bu(fmaxf(acc[3] + bia[3], 0.f)) << 16);
            *(uint2*)(h1 + ag * H1_AS + p * H1_RS + ocr) = make_uint2(lo, hi);
        }
    }
    __syncthreads();

    // ---- conv2: M=64 (4 Mt = wave), K=96 (3 taps x 32), N=80 (5 Nt) ----
    {
        int Mt = wave;
        int oc = Mt * 16 + col;
        s8v a[3];
#pragma unroll
        for (int ks = 0; ks < 3; ks++)
            a[ks] = *(const s8v*)(g_w2p + oc * 96 + ks * 32 + quad * 8);
        int ocr = Mt * 16 + quad * 4;
        f4v bia = *(const f4v*)(g_b2 + ocr);
#pragma unroll
        for (int Nt = 0; Nt < 5; Nt++) {
            int n = Nt * 16 + col;
            int ag = n / 5, p = n % 5;
            f4v acc = {0.f, 0.f, 0.f, 0.f};
#pragma unroll
            for (int ks = 0; ks < 3; ks++) {
                s8v b = *(const s8v*)(h1 + ag * H1_AS + (2 * p + ks) * H1_RS + quad * 8);
                acc = MFMA16(a[ks], b, acc);
            }
            unsigned int lo = f2bu(fmaxf(acc[0] + bia[0], 0.f)) | ((unsigned int)f2bu(fmaxf(acc[1] + bia[1], 0.f)) << 16);
            unsigned int hi = f2bu(fmaxf(acc[2] + bia[2], 0.f)) | ((unsigned int)f2bu(fmaxf(acc[3] + bia[3], 0.f)) << 16);
            *(uint2*)(h2 + ag * H2_AS + (p + 1) * H2_RS + ocr) = make_uint2(lo, hi);
        }
    }
    __syncthreads();

    // ---- conv3: M=128 (8 Mt, 2/wave), K=192 (6 slices), N=48 (3 Nt) ----
#pragma unroll
    for (int m2 = 0; m2 < 2; m2++) {
        int Mt = wave * 2 + m2;
        int oc = Mt * 16 + col;
        s8v a[6];
#pragma unroll
        for (int ks = 0; ks < 6; ks++)
            a[ks] = *(const s8v*)(g_w3p + oc * 192 + ks * 32 + quad * 8);
        int ocr = Mt * 16 + quad * 4;
        f4v bia = *(const f4v*)(g_b3 + ocr);
#pragma unroll
        for (int Nt = 0; Nt < 3; Nt++) {
            int n = Nt * 16 + col;
            int ag = n / 3, p = n % 3;
            f4v acc = {0.f, 0.f, 0.f, 0.f};
#pragma unroll
            for (int ks = 0; ks < 6; ks++) {
                int kg = ks * 32 + quad * 8;
                int tap = kg >> 6, ic = kg & 63;
                s8v b = *(const s8v*)(h2 + ag * H2_AS + (2 * p + tap) * H2_RS + ic);
                acc = MFMA16(a[ks], b, acc);
            }
            unsigned int lo = f2bu(fmaxf(acc[0] + bia[0], 0.f)) | ((unsigned int)f2bu(fmaxf(acc[1] + bia[1], 0.f)) << 16);
            unsigned int hi = f2bu(fmaxf(acc[2] + bia[2], 0.f)) | ((unsigned int)f2bu(fmaxf(acc[3] + bia[3], 0.f)) << 16);
            *(uint2*)(c3 + ag * C3_AS + p * 128 + ocr) = make_uint2(lo, hi);
        }
    }
    __syncthreads();

    // ---- epilogue: mean over 3 positions, valid mask, + type_emb ----
    {
        int ag = tid >> 4;
        int ocg = (tid & 15) * 8;
        s8v x0 = *(const s8v*)(c3 + ag * C3_AS + ocg);
        s8v x1 = *(const s8v*)(c3 + ag * C3_AS + 128 + ocg);
        s8v x2 = *(const s8v*)(c3 + ag * C3_AS + 256 + ocg);
        int valid = s_valid[ag];
        long agl = agent0 + ag;
        int cat = category[agl];
#pragma unroll
        for (int j = 0; j < 8; j++) {
            float m = (bu2f((unsigned short)x0[j]) + bu2f((unsigned short)x1[j]) +
                       bu2f((unsigned short)x2[j])) * (1.f / 3.f);
            if (!valid) m = 0.f;
            float te = ldf<DT>(type_emb, cat * 128 + ocg + j);
            stf<DT>(out, agl * 128 + ocg + j, m + te);
        }
    }
}

// ---------------- stage 2: ego cross-attention, overwrites row a=0 ----------------
template <int DT>
__global__ __launch_bounds__(128) void stage2_kernel(
    const void* __restrict__ cs, const int* __restrict__ category,
    const void* __restrict__ se_w, const void* __restrict__ se_b,
    const void* __restrict__ pe, const void* __restrict__ query,
    const void* __restrict__ ipw, const void* __restrict__ ipb,
    const void* __restrict__ opw, const void* __restrict__ opb,
    const void* __restrict__ type_emb, void* __restrict__ out) {
    if (g_dtype != DT) return;
    int b = blockIdx.x, d = threadIdx.x;
    __shared__ float s_xe[6][128];
    __shared__ float s_qu[128];
    __shared__ float s_q[128];
    __shared__ float s_k[6][128];
    __shared__ float s_v[6][128];
    __shared__ float s_att[4][6];
    __shared__ float s_o[128];

    s_qu[d] = ldf<DT>(query, d);
#pragma unroll
    for (int s = 0; s < 6; s++) {
        float ego = ldf<DT>(cs, b * 6 + s);
        s_xe[s][d] = fmaf(ego, ldf<DT>(se_w, s * 128 + d),
                          ldf<DT>(se_b, s * 128 + d) + ldf<DT>(pe, s * 128 + d));
    }
    __syncthreads();

    float accq = ldf<DT>(ipb, d);
    float bk = ldf<DT>(ipb, 128 + d), bv = ldf<DT>(ipb, 256 + d);
    float acck[6], accv[6];
#pragma unroll
    for (int s = 0; s < 6; s++) { acck[s] = bk; accv[s] = bv; }
    for (int e = 0; e < 128; e++) {
        float wqe = ldf<DT>(ipw, (long)d * 128 + e);
        accq = fmaf(s_qu[e], wqe, accq);
        float wke = ldf<DT>(ipw, (long)(128 + d) * 128 + e);
        float wve = ldf<DT>(ipw, (long)(256 + d) * 128 + e);
#pragma unroll
        for (int s = 0; s < 6; s++) {
            float xe = s_xe[s][e];
            acck[s] = fmaf(xe, wke, acck[s]);
            accv[s] = fmaf(xe, wve, accv[s]);
        }
    }
    s_q[d] = accq;
#pragma unroll
    for (int s = 0; s < 6; s++) { s_k[s][d] = acck[s]; s_v[s][d] = accv[s]; }
    __syncthreads();

    if (d < 4) {
        float sc[6];
        float mx = -1e30f;
#pragma unroll
        for (int s = 0; s < 6; s++) {
            float t = 0.f;
            for (int q = 0; q < 32; q++) t = fmaf(s_q[d * 32 + q], s_k[s][d * 32 + q], t);
            t *= 0.17677669529663687f;
            sc[s] = t;
            mx = fmaxf(mx, t);
        }
        float sum = 0.f;
#pragma unroll
        for (int s = 0; s < 6; s++) { sc[s] = expf(sc[s] - mx); sum += sc[s]; }
        float inv = 1.f / sum;
#pragma unroll
        for (int s = 0; s < 6; s++) s_att[d][s] = sc[s] * inv;
    }
    __syncthreads();

    {
        int h = d >> 5;
        float o = 0.f;
#pragma unroll
        for (int s = 0; s < 6; s++) o = fmaf(s_att[h][s], s_v[s][d], o);
        s_o[d] = o;
    }
    __syncthreads();

    float acc = ldf<DT>(opb, d);
    for (int e = 0; e < 128; e++) acc = fmaf(s_o[e], ldf<DT>(opw, (long)d * 128 + e), acc);
    int cat = category[(long)b * AAG];
    stf<DT>(out, (long)b * AAG * 128 + d, acc + ldf<DT>(type_emb, cat * 128 + d));
}

extern "C" void kernel_launch(void* const* d_in, const int* in_sizes, int n_in,
                              void* d_out, int out_size, void* d_ws, size_t ws_size,
                              hipStream_t stream) {
    const void* position      = d_in[0];
    const void* heading       = d_in[1];
    const void* velocity      = d_in[2];
    const void* shape         = d_in[3];
    const void* current_state = d_in[4];
    const int*  category      = (const int*)d_in[5];
    const void* valid_mask    = d_in[6];
    const void* conv1_w = d_in[7];
    const void* conv1_b = d_in[8];
    const void* conv2_w = d_in[9];
    const void* conv2_b = d_in[10];
    const void* conv3_w = d_in[11];
    const void* conv3_b = d_in[12];
    const void* se_w    = d_in[13];
    const void* se_b    = d_in[14];
    const void* pos_embed = d_in[15];
    const void* query     = d_in[16];
    const void* in_proj_w = d_in[17];
    const void* in_proj_b = d_in[18];
    const void* out_proj_w = d_in[19];
    const void* out_proj_b = d_in[20];
    const void* type_emb   = d_in[21];

    hipLaunchKernelGGL(detect_kernel, dim3(1), dim3(256), 0, stream,
                       (const unsigned int*)position, (const unsigned char*)valid_mask);

    hipLaunchKernelGGL(prep_weights_kernel<0>, dim3(64), dim3(256), 0, stream,
                       conv1_w, conv1_b, conv2_w, conv2_b, conv3_w, conv3_b);
    hipLaunchKernelGGL(prep_weights_kernel<1>, dim3(64), dim3(256), 0, stream,
                       conv1_w, conv1_b, conv2_w, conv2_b, conv3_w, conv3_b);

    hipLaunchKernelGGL(stage1_kernel<0>, dim3(NAG / 16), dim3(256), 0, stream,
                       position, heading, velocity, shape, valid_mask, category, type_emb, d_out);
    hipLaunchKernelGGL(stage1_kernel<1>, dim3(NAG / 16), dim3(256), 0, stream,
                       position, heading, velocity, shape, valid_mask, category, type_emb, d_out);

    hipLaunchKernelGGL(stage2_kernel<0>, dim3(BB), dim3(128), 0, stream,
                       current_state, category, se_w, se_b, pos_embed, query,
                       in_proj_w, in_proj_b, out_proj_w, out_proj_b, type_emb, d_out);
    hipLaunchKernelGGL(stage2_kernel<1>, dim3(BB), dim3(128), 0, stream,
                       current_state, category, se_w, se_b, pos_embed, query,
                       in_proj_w, in_proj_b, out_proj_w, out_proj_b, type_emb, d_out);
}